// Round 13
// baseline (1272.769 us; speedup 1.0000x reference)
//
#include <hip/hip_runtime.h>
#include <math.h>

#define HW 16384
constexpr int C_ = 96;
constexpr int E_ = 192, DI_ = 384, NS_ = 16, R_ = 12, K_ = 4, NBLK_ = 8, GW_ = 48;
constexpr int L_ = 1024, CXP_ = 44; // R + 2*NS
constexpr int TC_ = 64;             // scan chunk length
constexpr int NCH_ = L_ / TC_;      // 16 chunks

__device__ __forceinline__ float lrelu_(float x){ return x >= 0.f ? x : 0.2f*x; }
__device__ __forceinline__ float sigmoid_(float x){ return 1.f/(1.f+expf(-x)); }
__device__ __forceinline__ float silu_(float x){ return x/(1.f+expf(-x)); }
__device__ __forceinline__ float softplus_(float x){ return fmaxf(x,0.f)+log1pf(expf(-fabsf(x))); }

// ---------------- all 4 weight transposes in one dispatch; grid 2304, tb (32,8)
__global__ void k_transAll(const float* __restrict__ peW, float* __restrict__ peWT,
                           const float* __restrict__ puW, float* __restrict__ puWT,
                           const float* __restrict__ inW, float* __restrict__ inWT,
                           const float* __restrict__ outW, float* __restrict__ outWT){
  __shared__ float t[32][33];
  int id = blockIdx.x;
  const float* in; float* out; int rows, cols, bx, by;
  if (id < 288){ in=peW; out=peWT; rows=192; cols=1536; bx=id%48; by=id/48; }
  else if (id < 576){ int r=id-288; in=puW; out=puWT; rows=1536; cols=192; bx=r%6; by=r/6; }
  else if (id < 1728){ int r=id-576; int z=r/144; int q=r%144;
    in=inW+(size_t)z*768*192; out=inWT+(size_t)z*768*192; rows=768; cols=192; bx=q%6; by=q/6; }
  else { int r=id-1728; int z=r/72; int q=r%72;
    in=outW+(size_t)z*192*384; out=outWT+(size_t)z*192*384; rows=192; cols=384; bx=q%12; by=q/12; }
  int r0=by*32, c0=bx*32, tx=threadIdx.x, ty=threadIdx.y;
  for (int i=0;i<32;i+=8){
    int r=r0+ty+i, c=c0+tx;
    if (r<rows && c<cols) t[ty+i][tx]=in[(size_t)r*cols+c];
  }
  __syncthreads();
  for (int i=0;i<32;i+=8){
    int c=c0+ty+i, r=r0+tx;
    if (r<rows && c<cols) out[(size_t)c*rows+r]=t[tx][ty+i];
  }
}

// ---------------- bn1 + per-channel mean/max stats; also zeroes LN-sum buffers
__global__ void k_bn1(const float* __restrict__ x, const float* g, const float* b,
                      const float* m, const float* v,
                      float* __restrict__ h, float* __restrict__ stats,
                      float* __restrict__ su, float* __restrict__ sq){
  int c = blockIdx.x, tid = threadIdx.x;
  int gid = c*256 + tid;
  if (gid < 1024){ su[gid] = 0.f; sq[gid] = 0.f; }
  float sc = g[c]*rsqrtf(v[c]+1e-5f), sh = b[c]-m[c]*sc;
  const float* xc = x + (size_t)c*HW;
  float* hc = h + (size_t)c*HW;
  float s = 0.f, mx = -1e30f;
  for (int i=tid;i<HW;i+=256){
    float val = fmaf(xc[i], sc, sh);
    hc[i] = val; s += val; mx = fmaxf(mx, val);
  }
  for (int o=32;o;o>>=1){ s += __shfl_xor(s,o); mx = fmaxf(mx, __shfl_xor(mx,o)); }
  __shared__ float ss[4], sm[4];
  int wid = tid>>6, lane = tid&63;
  if (!lane){ ss[wid]=s; sm[wid]=mx; }
  __syncthreads();
  if (!tid){
    stats[c] = (ss[0]+ss[1]+ss[2]+ss[3])*(1.f/HW);
    stats[96+c] = fmaxf(fmaxf(sm[0],sm[1]),fmaxf(sm[2],sm[3]));
  }
}

// ---------------- channel-attention MLP (1 block)
__global__ void k_attn(const float* __restrict__ stats, const float* __restrict__ w1,
                       const float* __restrict__ w2, float* __restrict__ attn){
  __shared__ float hid[12];
  int tid = threadIdx.x;
  if (tid < 12){
    int j = tid%6, which = tid/6;
    const float* vv = stats + which*96;
    float a = 0.f;
    for (int c=0;c<96;c++) a += vv[c]*w1[j*96+c];
    hid[tid] = fmaxf(a, 0.f);
  }
  __syncthreads();
  if (tid < 96){
    float a = 0.f;
    for (int j=0;j<6;j++) a += (hid[j]+hid[6+j])*w2[tid*6+j];
    attn[tid] = sigmoid_(a);
  }
}

// ---------------- pe GEMM: A = patchified bufH (fused addressing), + bias + LN-stat atomics
__global__ __launch_bounds__(256) void k_gemmPE(const float* __restrict__ hsrc,
                      const float* __restrict__ wt, const float* __restrict__ bias,
                      float* __restrict__ out, float* __restrict__ su, float* __restrict__ sq){
  const int K = 1536, N = 192;
  __shared__ float As[32][34];
  __shared__ float Bs[32][32];
  int tid = threadIdx.x;
  int m0 = blockIdx.x*32, n0 = blockIdx.y*32;
  int tx = tid&15, ty = tid>>4;
  int arow = tid>>3, akq = tid&7;
  int brow = tid>>3, bn4 = tid&7;
  int m = m0+arow;
  int base2 = (m>>5)*512 + (m&31)*4;
  auto aload = [&](int kk)->float4 {
    int c = kk>>4, i2 = (kk>>2)&3;
    return *(const float4*)&hsrc[((size_t)c<<14) + (size_t)(i2*128 + base2)];
  };
  float4 aR = aload(akq*4);
  float4 bR = *(const float4*)&wt[(size_t)brow*N + n0 + bn4*4];
  float acc[2][2] = {{0}};
  for (int k0=0; k0<K; k0+=32){
    __syncthreads();
    As[akq*4+0][arow]=aR.x; As[akq*4+1][arow]=aR.y;
    As[akq*4+2][arow]=aR.z; As[akq*4+3][arow]=aR.w;
    *(float4*)&Bs[brow][bn4*4] = bR;
    __syncthreads();
    if (k0+32 < K){
      aR = aload(k0+32+akq*4);
      bR = *(const float4*)&wt[(size_t)(k0+32+brow)*N + n0 + bn4*4];
    }
    #pragma unroll
    for (int kk=0; kk<32; kk++){
      float2 av = *(const float2*)&As[kk][ty*2];
      float2 bv = *(const float2*)&Bs[kk][tx*2];
      acc[0][0] = fmaf(av.x, bv.x, acc[0][0]);
      acc[0][1] = fmaf(av.x, bv.y, acc[0][1]);
      acc[1][0] = fmaf(av.y, bv.x, acc[1][0]);
      acc[1][1] = fmaf(av.y, bv.y, acc[1][1]);
    }
  }
  float2 bq = *(const float2*)&bias[n0+tx*2];
  float sl[2], ql[2];
  #pragma unroll
  for (int i=0;i<2;i++){
    size_t o = (size_t)(m0+ty*2+i)*N + n0 + tx*2;
    float2 ov; ov.x = acc[i][0]+bq.x; ov.y = acc[i][1]+bq.y;
    *(float2*)&out[o] = ov;
    sl[i] = ov.x+ov.y; ql[i] = ov.x*ov.x+ov.y*ov.y;
  }
  #pragma unroll
  for (int o=8;o;o>>=1){
    sl[0]+=__shfl_xor(sl[0],o); ql[0]+=__shfl_xor(ql[0],o);
    sl[1]+=__shfl_xor(sl[1],o); ql[1]+=__shfl_xor(ql[1],o);
  }
  if (tx==0){
    atomicAdd(&su[m0+ty*2],   sl[0]); atomicAdd(&sq[m0+ty*2],   ql[0]);
    atomicAdd(&su[m0+ty*2+1], sl[1]); atomicAdd(&sq[m0+ty*2+1], ql[1]);
  }
}

// ---------------- gemm32 + residual + LN-stat atomics (outproj); grid (M/32,N/32)
__global__ __launch_bounds__(256) void k_gemm32s(const float* __restrict__ act,
                      const float* __restrict__ wt, const float* __restrict__ res,
                      float* __restrict__ out, float* __restrict__ su, float* __restrict__ sq,
                      int K, int N){
  __shared__ float As[32][34];
  __shared__ float Bs[32][32];
  int tid = threadIdx.x;
  int m0 = blockIdx.x*32, n0 = blockIdx.y*32;
  int tx = tid&15, ty = tid>>4;
  int arow = tid>>3, akq = tid&7;
  int brow = tid>>3, bn4 = tid&7;
  float4 aR = *(const float4*)&act[(size_t)(m0+arow)*K + akq*4];
  float4 bR = *(const float4*)&wt [(size_t)brow*N + n0 + bn4*4];
  float acc[2][2] = {{0}};
  for (int k0=0; k0<K; k0+=32){
    __syncthreads();
    As[akq*4+0][arow]=aR.x; As[akq*4+1][arow]=aR.y;
    As[akq*4+2][arow]=aR.z; As[akq*4+3][arow]=aR.w;
    *(float4*)&Bs[brow][bn4*4] = bR;
    __syncthreads();
    if (k0+32 < K){
      aR = *(const float4*)&act[(size_t)(m0+arow)*K + k0+32 + akq*4];
      bR = *(const float4*)&wt [(size_t)(k0+32+brow)*N + n0 + bn4*4];
    }
    #pragma unroll
    for (int kk=0; kk<32; kk++){
      float2 av = *(const float2*)&As[kk][ty*2];
      float2 bv = *(const float2*)&Bs[kk][tx*2];
      acc[0][0] = fmaf(av.x, bv.x, acc[0][0]);
      acc[0][1] = fmaf(av.x, bv.y, acc[0][1]);
      acc[1][0] = fmaf(av.y, bv.x, acc[1][0]);
      acc[1][1] = fmaf(av.y, bv.y, acc[1][1]);
    }
  }
  float sl[2], ql[2];
  #pragma unroll
  for (int i=0;i<2;i++){
    size_t o = (size_t)(m0+ty*2+i)*N + n0 + tx*2;
    float2 r = *(const float2*)&res[o];
    float2 ov; ov.x = acc[i][0]+r.x; ov.y = acc[i][1]+r.y;
    *(float2*)&out[o] = ov;
    sl[i] = ov.x+ov.y; ql[i] = ov.x*ov.x+ov.y*ov.y;
  }
  #pragma unroll
  for (int o=8;o;o>>=1){
    sl[0]+=__shfl_xor(sl[0],o); ql[0]+=__shfl_xor(ql[0],o);
    sl[1]+=__shfl_xor(sl[1],o); ql[1]+=__shfl_xor(ql[1],o);
  }
  if (tx==0){
    atomicAdd(&su[m0+ty*2],   sl[0]); atomicAdd(&sq[m0+ty*2],   ql[0]);
    atomicAdd(&su[m0+ty*2+1], sl[1]); atomicAdd(&sq[m0+ty*2+1], ql[1]);
  }
}

// ---------------- pu GEMM: bias, store un-patchified [c][h][w]; grid (32,48); K=192,N=1536
__global__ __launch_bounds__(256) void k_gemmPU(const float* __restrict__ act,
                      const float* __restrict__ wt, const float* __restrict__ bias,
                      float* __restrict__ out){
  const int K = 192, N = 1536;
  __shared__ float As[32][34];
  __shared__ float Bs[32][32];
  int tid = threadIdx.x;
  int m0 = blockIdx.x*32, n0 = blockIdx.y*32;
  int tx = tid&15, ty = tid>>4;
  int arow = tid>>3, akq = tid&7;
  int brow = tid>>3, bn4 = tid&7;
  float4 aR = *(const float4*)&act[(size_t)(m0+arow)*K + akq*4];
  float4 bR = *(const float4*)&wt [(size_t)brow*N + n0 + bn4*4];
  float acc[2][2] = {{0}};
  for (int k0=0; k0<K; k0+=32){
    __syncthreads();
    As[akq*4+0][arow]=aR.x; As[akq*4+1][arow]=aR.y;
    As[akq*4+2][arow]=aR.z; As[akq*4+3][arow]=aR.w;
    *(float4*)&Bs[brow][bn4*4] = bR;
    __syncthreads();
    if (k0+32 < K){
      aR = *(const float4*)&act[(size_t)(m0+arow)*K + k0+32 + akq*4];
      bR = *(const float4*)&wt [(size_t)(k0+32+brow)*N + n0 + bn4*4];
    }
    #pragma unroll
    for (int kk=0; kk<32; kk++){
      float2 av = *(const float2*)&As[kk][ty*2];
      float2 bv = *(const float2*)&Bs[kk][tx*2];
      acc[0][0] = fmaf(av.x, bv.x, acc[0][0]);
      acc[0][1] = fmaf(av.x, bv.y, acc[0][1]);
      acc[1][0] = fmaf(av.y, bv.x, acc[1][0]);
      acc[1][1] = fmaf(av.y, bv.y, acc[1][1]);
    }
  }
  int n = n0 + tx*2;
  float2 bq = *(const float2*)&bias[n];
  int c = n>>4, i2 = (n>>2)&3, j = n&3;
  #pragma unroll
  for (int i=0;i<2;i++){
    int m = m0+ty*2+i;
    size_t o = ((size_t)c<<14) + (size_t)((m>>5)*4+i2)*128 + (m&31)*4 + j;
    float2 ov; ov.x = acc[i][0]+bq.x; ov.y = acc[i][1]+bq.y;
    *(float2*)&out[o] = ov;
  }
}

// ---------------- gemm32 with layernorm fused on A (stats from raw sums); K%32==0
__global__ __launch_bounds__(256) void k_gemm32ln(const float* __restrict__ act,
                      const float* __restrict__ wt, const float* __restrict__ lg,
                      const float* __restrict__ lb, const float* __restrict__ su,
                      const float* __restrict__ sq, float* __restrict__ out,
                      int K, int N){
  __shared__ float As[32][34];
  __shared__ float Bs[32][32];
  int tid = threadIdx.x;
  int m0 = blockIdx.x*32, n0 = blockIdx.y*32;
  int tx = tid&15, ty = tid>>4;
  int arow = tid>>3, akq = tid&7;
  int brow = tid>>3, bn4 = tid&7;
  float m = su[m0+arow]*(1.f/192.f);
  float r = rsqrtf(sq[m0+arow]*(1.f/192.f) - m*m + 1e-5f);
  float4 aR = *(const float4*)&act[(size_t)(m0+arow)*K + akq*4];
  float4 gR = *(const float4*)&lg[akq*4];
  float4 hR = *(const float4*)&lb[akq*4];
  float4 bR = *(const float4*)&wt[(size_t)brow*N + n0 + bn4*4];
  float acc[2][2] = {{0}};
  for (int k0=0; k0<K; k0+=32){
    __syncthreads();
    As[akq*4+0][arow] = (aR.x-m)*r*gR.x + hR.x;
    As[akq*4+1][arow] = (aR.y-m)*r*gR.y + hR.y;
    As[akq*4+2][arow] = (aR.z-m)*r*gR.z + hR.z;
    As[akq*4+3][arow] = (aR.w-m)*r*gR.w + hR.w;
    *(float4*)&Bs[brow][bn4*4] = bR;
    __syncthreads();
    if (k0+32 < K){
      aR = *(const float4*)&act[(size_t)(m0+arow)*K + k0+32 + akq*4];
      gR = *(const float4*)&lg[k0+32+akq*4];
      hR = *(const float4*)&lb[k0+32+akq*4];
      bR = *(const float4*)&wt[(size_t)(k0+32+brow)*N + n0 + bn4*4];
    }
    #pragma unroll
    for (int kk=0; kk<32; kk++){
      float2 av = *(const float2*)&As[kk][ty*2];
      float2 bv = *(const float2*)&Bs[kk][tx*2];
      acc[0][0] = fmaf(av.x, bv.x, acc[0][0]);
      acc[0][1] = fmaf(av.x, bv.y, acc[0][1]);
      acc[1][0] = fmaf(av.y, bv.x, acc[1][0]);
      acc[1][1] = fmaf(av.y, bv.y, acc[1][1]);
    }
  }
  #pragma unroll
  for (int i=0;i<2;i++){
    size_t o = (size_t)(m0+ty*2+i)*N + n0 + tx*2;
    float2 ov; ov.x = acc[i][0]; ov.y = acc[i][1];
    *(float2*)&out[o] = ov;
  }
}

// ---------------- fused depthwise conv + silu + 2-layout xst build; grid (32 h0, 12 d0), tb (32,8)
__global__ __launch_bounds__(256) void k_dwxst(const float* __restrict__ xz,
                        const float* __restrict__ w, const float* __restrict__ bias,
                        float* __restrict__ xcs, float* __restrict__ xst0,
                        float* __restrict__ xst1){
  __shared__ float ld[96][33];
  __shared__ float t[32][33];
  int h0 = blockIdx.x;
  int d0 = blockIdx.y*32;
  int tx = threadIdx.x, ty = threadIdx.y;
  #pragma unroll
  for (int i=0;i<12;i++){
    int ll = i*8 + ty;
    int h = h0 - 1 + (ll>>5);
    int wv = ll & 31;
    float v = 0.f;
    if ((unsigned)h < 32u) v = xz[(size_t)(h*32+wv)*768 + d0 + tx];
    ld[ll][tx] = v;
  }
  __syncthreads();
  #pragma unroll
  for (int i=0;i<4;i++){
    int dl = ty + 8*i;
    int d = d0 + dl;
    float acc = bias[d];
    const float* wp = w + d*9;
    #pragma unroll
    for (int di=0;di<3;di++){
      #pragma unroll
      for (int dj=0;dj<3;dj++){
        int wq = tx + dj - 1;
        if ((unsigned)wq < 32u)
          acc = fmaf(ld[di*32 + wq][dl], wp[di*3+dj], acc);
      }
    }
    float val = silu_(acc);
    xcs[(size_t)d*L_ + h0*32 + tx] = val;
    t[dl][tx] = val;
  }
  __syncthreads();
  int d = d0 + tx;
  #pragma unroll
  for (int i=0;i<4;i++){
    int wq = ty + 8*i;
    int l = h0*32 + wq;
    float val = t[tx][wq];
    int t1 = wq*32 + h0;
    xst0[(size_t)l*DI_ + d] = val;
    xst1[(size_t)t1*DI_ + d] = val;
  }
}

// ---------------- x_dbl partial (split-K over d, 3 x 128): grid (4, 11, 12)
__global__ __launch_bounds__(256) void k_xdblP(const float* __restrict__ xcs,
                       const float* __restrict__ xw, float* __restrict__ xdblP){
  int kz = blockIdx.z;
  int k = kz & 3, sp = kz >> 2;
  int s = blockIdx.x*256 + threadIdx.x;
  int Ts = ((s&31)<<5) | (s>>5);
  int lw;
  if (k==0) lw = s;
  else if (k==1) lw = Ts;
  else if (k==2) lw = 1023-s;
  else lw = 1023-Ts;
  int c0 = blockIdx.y*4;
  const float* wp = xw + ((size_t)k*CXP_ + c0)*DI_ + sp*128;
  const float* src = xcs + s + (size_t)sp*128*L_;
  float a0=0,a1=0,a2=0,a3=0;
  for (int d=0; d<128; d++){
    float v = src[(size_t)d*L_];
    a0 = fmaf(v, wp[d],        a0);
    a1 = fmaf(v, wp[DI_+d],    a1);
    a2 = fmaf(v, wp[2*DI_+d],  a2);
    a3 = fmaf(v, wp[3*DI_+d],  a3);
  }
  size_t base = (((size_t)sp*4 + k)*CXP_ + c0)*L_ + lw;
  xdblP[base]       = a0;
  xdblP[base+L_]    = a1;
  xdblP[base+2*L_]  = a2;
  xdblP[base+3*L_]  = a3;
}

// ---------------- combine partials + dt proj + softplus -> dts_t; repack B,C -> bc
__global__ void k_dtbc(const float* __restrict__ xdblP, const float* __restrict__ dtw,
                       const float* __restrict__ dtb, float* __restrict__ dts_t,
                       float* __restrict__ bc){
  int k = blockIdx.y, l = blockIdx.x, d = threadIdx.x;
  const float* p0 = xdblP + ((size_t)(0+k)*CXP_)*L_ + l;
  const float* p1 = xdblP + ((size_t)(4+k)*CXP_)*L_ + l;
  const float* p2 = xdblP + ((size_t)(8+k)*CXP_)*L_ + l;
  float acc = dtb[(size_t)k*DI_ + d];
  const float* w = dtw + ((size_t)k*DI_ + d)*R_;
  #pragma unroll
  for (int r=0;r<R_;r++){
    size_t o = (size_t)r*L_;
    acc = fmaf(p0[o]+p1[o]+p2[o], w[r], acc);
  }
  dts_t[((size_t)k*L_ + l)*DI_ + d] = softplus_(acc);
  if (d < 32){
    size_t o = (size_t)(R_+d)*L_;
    bc[((size_t)k*L_ + l)*32 + d] = p0[o]+p1[o]+p2[o];
  }
}

// ---------------- chunked selective scan, phase A
__global__ __launch_bounds__(256) void k_scanA(const float* __restrict__ xst0,
                      const float* __restrict__ xst1,
                      const float* __restrict__ dts_t, const float* __restrict__ bc,
                      const float* __restrict__ Alog,
                      float* __restrict__ Ech, float* __restrict__ Hch){
  int k = blockIdx.z;
  int d = blockIdx.y*16 + (threadIdx.x>>4);
  int n = threadIdx.x&15;
  int ch = blockIdx.x;
  float A = -expf(Alog[((size_t)k*DI_ + d)*NS_ + n]);
  float aL2 = A * 1.4426950408889634f;
  int t0 = ch*TC_;
  const float* dtp = dts_t + ((size_t)k*L_ + t0)*DI_ + d;
  const float* bcp = bc    + ((size_t)k*L_ + t0)*32;
  const float* xb = (k&1) ? xst1 : xst0;
  const float* xp_; ptrdiff_t xs_;
  if (k < 2){ xp_ = xb + (size_t)t0*DI_ + d; xs_ = DI_; }
  else      { xp_ = xb + (size_t)(1023-t0)*DI_ + d; xs_ = -(ptrdiff_t)DI_; }
  float h = 0.f, Ep = 1.f;
  #pragma unroll 4
  for (int t=0;t<TC_;t++){
    float dt = dtp[(size_t)t*DI_];
    float xv = xp_[(ptrdiff_t)t*xs_];
    float Bn = bcp[t*32+n];
    float e = exp2f(aL2*dt);
    h = fmaf(e, h, dt*xv*Bn);
    Ep *= e;
  }
  size_t idx = (((size_t)k*NCH_ + ch)*DI_ + d)*NS_ + n;
  Ech[idx] = Ep; Hch[idx] = h;
}

// ---------------- phase B: fold chunk aggregates -> carry-in per chunk
__global__ void k_scanB(const float* __restrict__ Ech, const float* __restrict__ Hch,
                        float* __restrict__ carry){
  int idx = blockIdx.x*256 + threadIdx.x;
  int k = idx / (DI_*NS_);
  int dn = idx % (DI_*NS_);
  float h = 0.f;
  #pragma unroll
  for (int c=0;c<NCH_;c++){
    size_t o = ((size_t)(k*NCH_+c)*DI_*NS_) + dn;
    carry[o] = h;
    h = fmaf(Ech[o], h, Hch[o]);
  }
}

// ---------------- phase C: recompute with carry-in, emit y
__global__ __launch_bounds__(256) void k_scanC(const float* __restrict__ xst0,
                      const float* __restrict__ xst1,
                      const float* __restrict__ dts_t, const float* __restrict__ bc,
                      const float* __restrict__ Alog, const float* __restrict__ carry,
                      float* __restrict__ yst){
  int k = blockIdx.z;
  int d = blockIdx.y*16 + (threadIdx.x>>4);
  int n = threadIdx.x&15;
  int ch = blockIdx.x;
  float A = -expf(Alog[((size_t)k*DI_ + d)*NS_ + n]);
  float aL2 = A * 1.4426950408889634f;
  int t0 = ch*TC_;
  const float* dtp = dts_t + ((size_t)k*L_ + t0)*DI_ + d;
  const float* bcp = bc    + ((size_t)k*L_ + t0)*32;
  const float* xb = (k&1) ? xst1 : xst0;
  const float* xp_; ptrdiff_t xs_;
  if (k < 2){ xp_ = xb + (size_t)t0*DI_ + d; xs_ = DI_; }
  else      { xp_ = xb + (size_t)(1023-t0)*DI_ + d; xs_ = -(ptrdiff_t)DI_; }
  float* yp = yst + ((size_t)k*L_ + t0)*DI_ + d;
  float h = carry[(((size_t)k*NCH_ + ch)*DI_ + d)*NS_ + n];
  #pragma unroll 4
  for (int t=0;t<TC_;t++){
    float dt = dtp[(size_t)t*DI_];
    float xv = xp_[(ptrdiff_t)t*xs_];
    float Bn = bcp[t*32+n], Cn = bcp[t*32+16+n];
    float e = exp2f(aL2*dt);
    h = fmaf(e, h, dt*xv*Bn);
    float p = h*Cn;
    p += __shfl_xor(p,1); p += __shfl_xor(p,2);
    p += __shfl_xor(p,4); p += __shfl_xor(p,8);
    if (n==0) yp[(size_t)t*DI_] = p;
  }
}

// ---------------- merge 4 dirs + Dskip + LN + silu(z) gate; zeroes LN-sum bufs
__global__ void k_merge(const float* __restrict__ yst, const float* __restrict__ xst0,
                        const float* __restrict__ xst1,
                        const float* __restrict__ Dsk, const float* __restrict__ mw,
                        const float* __restrict__ ong, const float* __restrict__ onb,
                        const float* __restrict__ xz, float* __restrict__ out,
                        float* __restrict__ su, float* __restrict__ sq){
  int l = blockIdx.x, d = threadIdx.x;
  if (d == 0){ su[l] = 0.f; sq[l] = 0.f; }
  int T = ((l&31)<<5) | (l>>5);
  int tt[4] = { l, T, 1023-l, 1023-T };
  float xv0 = xst0[(size_t)l*DI_ + d];
  float xv1 = xst1[(size_t)T*DI_ + d];
  float v = 0.f;
  #pragma unroll
  for (int k=0;k<4;k++){
    float xk = (k&1) ? xv1 : xv0;
    v += mw[k]*(yst[(size_t)(k*L_ + tt[k])*DI_ + d] + xk*Dsk[k*DI_+d]);
  }
  float s = v, sqv = v*v;
  for (int o=32;o;o>>=1){ s += __shfl_xor(s,o); sqv += __shfl_xor(sqv,o); }
  __shared__ float rs_[6], rq_[6];
  int lane = d&63, wid = d>>6;
  if (!lane){ rs_[wid]=s; rq_[wid]=sqv; }
  __syncthreads();
  float ts=0.f, tq=0.f;
  #pragma unroll
  for (int i=0;i<6;i++){ ts += rs_[i]; tq += rq_[i]; }
  float mu = ts*(1.f/DI_);
  float rstd = rsqrtf(tq*(1.f/DI_) - mu*mu + 1e-5f);
  float y = (v-mu)*rstd*ong[d] + onb[d];
  float z = xz[(size_t)l*768 + DI_ + d];
  out[(size_t)l*DI_ + d] = y * silu_(z);
}

// ---------------- residual + attention + bn2 (xu already in [c][h][w])
__global__ void k_sum(const float* __restrict__ x, const float* __restrict__ h,
                      const float* __restrict__ attn, const float* __restrict__ xu,
                      const float* g2, const float* b2, const float* m2, const float* v2,
                      float* __restrict__ xsum, float* __restrict__ h2){
  int idx = blockIdx.x*256 + threadIdx.x;
  int c = idx>>14;
  float s = x[idx] + h[idx]*attn[c] + xu[idx];
  xsum[idx] = s;
  h2[idx] = (s - m2[c])*rsqrtf(v2[c]+1e-5f)*g2[c] + b2[c];
}

// ---------------- scpa: dual 1x1 conv + lrelu; 6+6 oc per block; grid (64,8) sp-major
__global__ __launch_bounds__(256) void k_1x1ab(const float* __restrict__ h2,
                        const float* __restrict__ wa, const float* __restrict__ wb,
                        float* __restrict__ a, float* __restrict__ b){
  __shared__ float lw[96*12];
  int ocg = blockIdx.y;
  for (int i=threadIdx.x; i<96*12; i+=256){
    int o = i%12, c = i/12;
    lw[i] = (o<6) ? wa[(ocg*6 + o)*96 + c] : wb[(ocg*6 + (o-6))*96 + c];
  }
  __syncthreads();
  int p = blockIdx.x*256 + threadIdx.x;
  float acc[12];
  #pragma unroll
  for (int o=0;o<12;o++) acc[o]=0.f;
  for (int c=0;c<96;c++){
    float v = h2[(size_t)c*HW + p];
    const float* w = lw + c*12;
    #pragma unroll
    for (int o=0;o<12;o++) acc[o] = fmaf(v, w[o], acc[o]);
  }
  #pragma unroll
  for (int o=0;o<6;o++){
    a[(size_t)(ocg*6+o)*HW + p] = lrelu_(acc[o]);
    b[(size_t)(ocg*6+o)*HW + p] = lrelu_(acc[6+o]);
  }
}

// ---------------- scpa: DUAL 3x3 conv (k1 + k3 paths) with fused sigmoid gate on B path
// grid (64 sp, 16 half*ocg); B-half computes gate = sigmoid(k2·b + k2b) inline from staged center rows
__global__ __launch_bounds__(256) void k_conv3d(const float* __restrict__ inA,
                        const float* __restrict__ wA, const float* __restrict__ inB,
                        const float* __restrict__ wB,
                        const float* __restrict__ k2w, const float* __restrict__ k2b,
                        float* __restrict__ outA, float* __restrict__ outB){
  __shared__ float lw[48*9*6];
  __shared__ float lg[48*6];
  __shared__ float ld[8][4][130];
  int sp = blockIdx.x;
  int half = blockIdx.y >> 3;
  int ocg = blockIdx.y & 7;
  const float* in = half ? inB : inA;
  const float* w  = half ? wB : wA;
  int tid = threadIdx.x;
  for (int i=tid; i<48*9*6; i+=256){
    int o = i%6, j = (i/6)%9, ic = i/54;
    lw[i] = w[((size_t)(ocg*6+o)*48 + ic)*9 + j];
  }
  if (half){
    for (int i=tid; i<48*6; i+=256){
      int o = i%6, c = i/6;
      lg[i] = k2w[(ocg*6 + o)*48 + c];
    }
  }
  if (tid < 32){ ld[tid>>2][tid&3][0] = 0.f; ld[tid>>2][tid&3][129] = 0.f; }
  int p = sp*256 + tid;
  int ww = p&127;
  int hbase = sp*2 - 1;                      // rows hbase..hbase+3
  int lr = 1 + (tid>>7);                     // this thread's center row in ld
  float acc[6], gacc[6];
  #pragma unroll
  for (int o=0;o<6;o++){ acc[o]=0.f; gacc[o]=0.f; }
  for (int ic0=0; ic0<48; ic0+=8){
    __syncthreads();
    #pragma unroll
    for (int q=0;q<16;q++){
      int i = tid + q*256;
      int icl = i>>9, rem = i&511;
      int r = rem>>7, cp = rem&127;
      int gy = hbase + r;
      ld[icl][r][cp+1] = ((unsigned)gy < 128u) ? in[(size_t)(ic0+icl)*HW + gy*128 + cp] : 0.f;
    }
    __syncthreads();
    #pragma unroll
    for (int icl=0; icl<8; icl++){
      const float* lwp = lw + (ic0+icl)*54;
      #pragma unroll
      for (int di=0;di<3;di++){
        #pragma unroll
        for (int dj=0;dj<3;dj++){
          float xv = ld[icl][lr-1+di][ww+dj];
          const float* wj = lwp + (di*3+dj)*6;
          #pragma unroll
          for (int o=0;o<6;o++) acc[o] = fmaf(xv, wj[o], acc[o]);
        }
      }
      if (half){
        float cv = ld[icl][lr][ww+1];
        const float* gj = lg + (ic0+icl)*6;
        #pragma unroll
        for (int o=0;o<6;o++) gacc[o] = fmaf(cv, gj[o], gacc[o]);
      }
    }
  }
  if (half == 0){
    #pragma unroll
    for (int o=0;o<6;o++)
      outA[(size_t)(ocg*6+o)*HW + p] = lrelu_(acc[o]);
  } else {
    #pragma unroll
    for (int o=0;o<6;o++){
      size_t oi = (size_t)(ocg*6+o)*HW + p;
      outB[oi] = acc[o]*sigmoid_(gacc[o] + k2b[ocg*6+o]);
    }
  }
}

// ---------------- scpa: single 3x3 conv (k4, lrelu); grid (64 sp, 8 ocg)
__global__ __launch_bounds__(256) void k_conv3(const float* __restrict__ in,
                        const float* __restrict__ w, float* __restrict__ out){
  __shared__ float lw[48*9*6];
  __shared__ float ld[8][4][130];
  int sp = blockIdx.x;
  int ocg = blockIdx.y;
  int tid = threadIdx.x;
  for (int i=tid; i<48*9*6; i+=256){
    int o = i%6, j = (i/6)%9, ic = i/54;
    lw[i] = w[((size_t)(ocg*6+o)*48 + ic)*9 + j];
  }
  if (tid < 32){ ld[tid>>2][tid&3][0] = 0.f; ld[tid>>2][tid&3][129] = 0.f; }
  int p = sp*256 + tid;
  int ww = p&127;
  int hbase = sp*2 - 1;
  int lr = 1 + (tid>>7);
  float acc[6];
  #pragma unroll
  for (int o=0;o<6;o++) acc[o]=0.f;
  for (int ic0=0; ic0<48; ic0+=8){
    __syncthreads();
    #pragma unroll
    for (int q=0;q<16;q++){
      int i = tid + q*256;
      int icl = i>>9, rem = i&511;
      int r = rem>>7, cp = rem&127;
      int gy = hbase + r;
      ld[icl][r][cp+1] = ((unsigned)gy < 128u) ? in[(size_t)(ic0+icl)*HW + gy*128 + cp] : 0.f;
    }
    __syncthreads();
    #pragma unroll
    for (int icl=0; icl<8; icl++){
      const float* lwp = lw + (ic0+icl)*54;
      #pragma unroll
      for (int di=0;di<3;di++){
        #pragma unroll
        for (int dj=0;dj<3;dj++){
          float xv = ld[icl][lr-1+di][ww+dj];
          const float* wj = lwp + (di*3+dj)*6;
          #pragma unroll
          for (int o=0;o<6;o++) acc[o] = fmaf(xv, wj[o], acc[o]);
        }
      }
    }
  }
  #pragma unroll
  for (int o=0;o<6;o++)
    out[(size_t)(ocg*6+o)*HW + p] = lrelu_(acc[o]);
}

// ---------------- final 1x1 conv + both residuals; grid (64,8) sp-major
__global__ __launch_bounds__(256) void k_c3(const float* __restrict__ ab,
                     const float* __restrict__ w, const float* __restrict__ h2,
                     const float* __restrict__ xsum, float* __restrict__ out){
  __shared__ float lw[96*12];
  int ocg = blockIdx.y;
  for (int i=threadIdx.x; i<96*12; i+=256){
    int o = i%12, j = i/12;
    lw[i] = w[(ocg*12 + o)*96 + j];
  }
  __syncthreads();
  int p = blockIdx.x*256 + threadIdx.x;
  float acc[12];
  #pragma unroll
  for (int o=0;o<12;o++) acc[o]=0.f;
  for (int j=0;j<96;j++){
    float v = ab[(size_t)j*HW + p];
    const float* wp = lw + j*12;
    #pragma unroll
    for (int o=0;o<12;o++) acc[o] = fmaf(v, wp[o], acc[o]);
  }
  #pragma unroll
  for (int o=0;o<12;o++){
    size_t oi = (size_t)(ocg*12+o)*HW + p;
    out[oi] = acc[o] + h2[oi] + xsum[oi];
  }
}

extern "C" void kernel_launch(void* const* d_in, const int* in_sizes, int n_in,
                              void* d_out, int out_size, void* d_ws, size_t ws_size,
                              hipStream_t stream){
  (void)in_sizes; (void)n_in; (void)out_size; (void)ws_size;
  const float* x    = (const float*)d_in[0];
  const float* bn1g = (const float*)d_in[1];
  const float* bn1b = (const float*)d_in[2];
  const float* bn1m = (const float*)d_in[3];
  const float* bn1v = (const float*)d_in[4];
  const float* caw1 = (const float*)d_in[5];
  const float* caw2 = (const float*)d_in[6];
  const float* peW  = (const float*)d_in[7];
  const float* peb  = (const float*)d_in[8];
  const float* puW  = (const float*)d_in[9];
  const float* pub  = (const float*)d_in[10];
  const float* lng  = (const float*)d_in[11];
  const float* lnb  = (const float*)d_in[12];
  const float* inW  = (const float*)d_in[13];
  const float* convw= (const float*)d_in[14];
  const float* convb= (const float*)d_in[15];
  const float* xprojw=(const float*)d_in[16];
  const float* dtw  = (const float*)d_in[17];
  const float* dtb  = (const float*)d_in[18];
  const float* Alog = (const float*)d_in[19];
  const float* Dsk  = (const float*)d_in[20];
  const float* ong  = (const float*)d_in[21];
  const float* onb  = (const float*)d_in[22];
  const float* outW = (const float*)d_in[23];
  const float* mw   = (const float*)d_in[24];
  const float* bn2g = (const float*)d_in[25];
  const float* bn2b = (const float*)d_in[26];
  const float* bn2m = (const float*)d_in[27];
  const float* bn2v = (const float*)d_in[28];
  const float* c1a  = (const float*)d_in[29];
  const float* c1b  = (const float*)d_in[30];
  const float* k1w  = (const float*)d_in[31];
  const float* k2w  = (const float*)d_in[32];
  const float* k2b  = (const float*)d_in[33];
  const float* k3w  = (const float*)d_in[34];
  const float* k4w  = (const float*)d_in[35];
  const float* c3w  = (const float*)d_in[36];
  float* out = (float*)d_out;

  float* ws = (float*)d_ws;
  size_t off = 0;
  auto alloc = [&](size_t n){ float* p = ws + off; off += n; return p; };
  float* peWT  = alloc((size_t)1536*192);
  float* puWT  = alloc((size_t)192*1536);
  float* inWT  = alloc((size_t)8*192*768);
  float* outWT = alloc((size_t)8*384*192);
  float* bufH  = alloc((size_t)96*HW);
  float* stats = alloc(256);
  float* attn  = alloc(128);
  float* bufP  = alloc((size_t)1024*1536);   // xu ([c][h][w] layout)
  float* x2a   = alloc((size_t)1024*192);
  float* x2b   = alloc((size_t)1024*192);
  float* bufXZ = alloc((size_t)1024*768);
  float* bufXCS= alloc((size_t)384*1024);
  float* bufXST= alloc((size_t)4*1024*384);  // xst0|xst1 (half used); later ab (96ch)
  float* xdblP = alloc((size_t)12*44*1024);
  float* dts   = alloc((size_t)4*1024*384);  // scan dts; scpa a|b
  float* bc    = alloc((size_t)4*1024*32);
  float* yst   = alloc((size_t)4*1024*384);  // scan y; scpa t
  float* bufY  = alloc((size_t)1024*384);
  float* xsum  = alloc((size_t)96*HW);
  float* h2    = alloc((size_t)96*HW);
  float* Ech   = alloc((size_t)K_*NCH_*DI_*NS_);
  float* Hch   = alloc((size_t)K_*NCH_*DI_*NS_);
  float* carry = alloc((size_t)K_*NCH_*DI_*NS_);
  float* suB   = alloc(1024);
  float* sqB   = alloc(1024);
  float* xst0  = bufXST;
  float* xst1  = bufXST + (size_t)L_*DI_;

  dim3 tb(32,8);
  k_transAll<<<2304, tb, 0, stream>>>(peW, peWT, puW, puWT, inW, inWT, outW, outWT);

  k_bn1<<<96,256,0,stream>>>(x, bn1g, bn1b, bn1m, bn1v, bufH, stats, suB, sqB);
  k_attn<<<1,128,0,stream>>>(stats, caw1, caw2, attn);
  k_gemmPE<<<dim3(32,6),256,0,stream>>>(bufH, peWT, peb, x2a, suB, sqB);

  float* cur = x2a; float* nxt = x2b;
  for (int b=0;b<8;b++){
    k_gemm32ln<<<dim3(32,24),256,0,stream>>>(cur, inWT+(size_t)b*192*768,
                        lng+(size_t)b*192, lnb+(size_t)b*192, suB, sqB, bufXZ, 192, 768);
    k_dwxst<<<dim3(32,12),tb,0,stream>>>(bufXZ, convw+(size_t)b*384*9,
                        convb+(size_t)b*384, bufXCS, xst0, xst1);
    k_xdblP<<<dim3(4,11,12),256,0,stream>>>(bufXCS, xprojw+(size_t)b*4*44*384, xdblP);
    k_dtbc<<<dim3(1024,4),384,0,stream>>>(xdblP, dtw+(size_t)b*4*384*12, dtb+(size_t)b*4*384, dts, bc);
    const float* Ab = Alog + (size_t)b*4*384*16;
    k_scanA<<<dim3(NCH_,DI_/16,4),256,0,stream>>>(xst0, xst1, dts, bc, Ab, Ech, Hch);
    k_scanB<<<(K_*DI_*NS_)/256,256,0,stream>>>(Ech, Hch, carry);
    k_scanC<<<dim3(NCH_,DI_/16,4),256,0,stream>>>(xst0, xst1, dts, bc, Ab, carry, yst);
    k_merge<<<1024,384,0,stream>>>(yst, xst0, xst1, Dsk+(size_t)b*4*384, mw+(size_t)b*4,
                                   ong+(size_t)b*384, onb+(size_t)b*384, bufXZ, bufY, suB, sqB);
    k_gemm32s<<<dim3(32,6),256,0,stream>>>(bufY, outWT+(size_t)b*384*192, cur, nxt, suB, sqB, 384, 192);
    float* t = cur; cur = nxt; nxt = t;
  }

  k_gemmPU<<<dim3(32,48),256,0,stream>>>(cur, puWT, pub, bufP);
  k_sum<<<(96*HW)/256,256,0,stream>>>(x, bufH, attn, bufP, bn2g, bn2b, bn2m, bn2v, xsum, h2);

  float* bufA = dts;
  float* bufB = dts + (size_t)48*HW;
  float* bufT = yst;
  float* ab   = bufXST;
  k_1x1ab<<<dim3(64,8),256,0,stream>>>(h2, c1a, c1b, bufA, bufB);
  k_conv3d<<<dim3(64,16),256,0,stream>>>(bufA, k1w, bufB, k3w, k2w, k2b, ab, bufT);
  k_conv3<<<dim3(64,8),256,0,stream>>>(bufT, k4w, ab+(size_t)48*HW);
  k_c3<<<dim3(64,8),256,0,stream>>>(ab, c3w, h2, xsum, out);
}

// Round 14
// 1112.995 us; speedup vs baseline: 1.1436x; 1.1436x over previous
//
#include <hip/hip_runtime.h>
#include <math.h>

#define HW 16384
constexpr int C_ = 96;
constexpr int E_ = 192, DI_ = 384, NS_ = 16, R_ = 12, K_ = 4, NBLK_ = 8, GW_ = 48;
constexpr int L_ = 1024, CXP_ = 44; // R + 2*NS
constexpr int TC_ = 64;             // scan chunk length
constexpr int NCH_ = L_ / TC_;      // 16 chunks

__device__ __forceinline__ float lrelu_(float x){ return x >= 0.f ? x : 0.2f*x; }
__device__ __forceinline__ float sigmoid_(float x){ return 1.f/(1.f+expf(-x)); }
__device__ __forceinline__ float silu_(float x){ return x/(1.f+expf(-x)); }
__device__ __forceinline__ float softplus_(float x){ return fmaxf(x,0.f)+log1pf(expf(-fabsf(x))); }

// ---------------- all 4 weight transposes in one dispatch; grid 2304, tb (32,8)
__global__ void k_transAll(const float* __restrict__ peW, float* __restrict__ peWT,
                           const float* __restrict__ puW, float* __restrict__ puWT,
                           const float* __restrict__ inW, float* __restrict__ inWT,
                           const float* __restrict__ outW, float* __restrict__ outWT){
  __shared__ float t[32][33];
  int id = blockIdx.x;
  const float* in; float* out; int rows, cols, bx, by;
  if (id < 288){ in=peW; out=peWT; rows=192; cols=1536; bx=id%48; by=id/48; }
  else if (id < 576){ int r=id-288; in=puW; out=puWT; rows=1536; cols=192; bx=r%6; by=r/6; }
  else if (id < 1728){ int r=id-576; int z=r/144; int q=r%144;
    in=inW+(size_t)z*768*192; out=inWT+(size_t)z*768*192; rows=768; cols=192; bx=q%6; by=q/6; }
  else { int r=id-1728; int z=r/72; int q=r%72;
    in=outW+(size_t)z*192*384; out=outWT+(size_t)z*192*384; rows=192; cols=384; bx=q%12; by=q/12; }
  int r0=by*32, c0=bx*32, tx=threadIdx.x, ty=threadIdx.y;
  for (int i=0;i<32;i+=8){
    int r=r0+ty+i, c=c0+tx;
    if (r<rows && c<cols) t[ty+i][tx]=in[(size_t)r*cols+c];
  }
  __syncthreads();
  for (int i=0;i<32;i+=8){
    int c=c0+ty+i, r=r0+tx;
    if (r<rows && c<cols) out[(size_t)c*rows+r]=t[tx][ty+i];
  }
}

// ---------------- bn1 + per-channel mean/max stats; also zeroes LN-sum buffers
__global__ void k_bn1(const float* __restrict__ x, const float* g, const float* b,
                      const float* m, const float* v,
                      float* __restrict__ h, float* __restrict__ stats,
                      float* __restrict__ su, float* __restrict__ sq){
  int c = blockIdx.x, tid = threadIdx.x;
  int gid = c*256 + tid;
  if (gid < 1024){ su[gid] = 0.f; sq[gid] = 0.f; }
  float sc = g[c]*rsqrtf(v[c]+1e-5f), sh = b[c]-m[c]*sc;
  const float* xc = x + (size_t)c*HW;
  float* hc = h + (size_t)c*HW;
  float s = 0.f, mx = -1e30f;
  for (int i=tid;i<HW;i+=256){
    float val = fmaf(xc[i], sc, sh);
    hc[i] = val; s += val; mx = fmaxf(mx, val);
  }
  for (int o=32;o;o>>=1){ s += __shfl_xor(s,o); mx = fmaxf(mx, __shfl_xor(mx,o)); }
  __shared__ float ss[4], sm[4];
  int wid = tid>>6, lane = tid&63;
  if (!lane){ ss[wid]=s; sm[wid]=mx; }
  __syncthreads();
  if (!tid){
    stats[c] = (ss[0]+ss[1]+ss[2]+ss[3])*(1.f/HW);
    stats[96+c] = fmaxf(fmaxf(sm[0],sm[1]),fmaxf(sm[2],sm[3]));
  }
}

// ---------------- channel-attention MLP (1 block)
__global__ void k_attn(const float* __restrict__ stats, const float* __restrict__ w1,
                       const float* __restrict__ w2, float* __restrict__ attn){
  __shared__ float hid[12];
  int tid = threadIdx.x;
  if (tid < 12){
    int j = tid%6, which = tid/6;
    const float* vv = stats + which*96;
    float a = 0.f;
    for (int c=0;c<96;c++) a += vv[c]*w1[j*96+c];
    hid[tid] = fmaxf(a, 0.f);
  }
  __syncthreads();
  if (tid < 96){
    float a = 0.f;
    for (int j=0;j<6;j++) a += (hid[j]+hid[6+j])*w2[tid*6+j];
    attn[tid] = sigmoid_(a);
  }
}

// ---------------- pe GEMM: A = patchified bufH (fused addressing), + bias + LN-stat atomics
__global__ __launch_bounds__(256) void k_gemmPE(const float* __restrict__ hsrc,
                      const float* __restrict__ wt, const float* __restrict__ bias,
                      float* __restrict__ out, float* __restrict__ su, float* __restrict__ sq){
  const int K = 1536, N = 192;
  __shared__ float As[32][34];
  __shared__ float Bs[32][32];
  int tid = threadIdx.x;
  int m0 = blockIdx.x*32, n0 = blockIdx.y*32;
  int tx = tid&15, ty = tid>>4;
  int arow = tid>>3, akq = tid&7;
  int brow = tid>>3, bn4 = tid&7;
  int m = m0+arow;
  int base2 = (m>>5)*512 + (m&31)*4;
  auto aload = [&](int kk)->float4 {
    int c = kk>>4, i2 = (kk>>2)&3;
    return *(const float4*)&hsrc[((size_t)c<<14) + (size_t)(i2*128 + base2)];
  };
  float4 aR = aload(akq*4);
  float4 bR = *(const float4*)&wt[(size_t)brow*N + n0 + bn4*4];
  float acc[2][2] = {{0}};
  for (int k0=0; k0<K; k0+=32){
    __syncthreads();
    As[akq*4+0][arow]=aR.x; As[akq*4+1][arow]=aR.y;
    As[akq*4+2][arow]=aR.z; As[akq*4+3][arow]=aR.w;
    *(float4*)&Bs[brow][bn4*4] = bR;
    __syncthreads();
    if (k0+32 < K){
      aR = aload(k0+32+akq*4);
      bR = *(const float4*)&wt[(size_t)(k0+32+brow)*N + n0 + bn4*4];
    }
    #pragma unroll
    for (int kk=0; kk<32; kk++){
      float2 av = *(const float2*)&As[kk][ty*2];
      float2 bv = *(const float2*)&Bs[kk][tx*2];
      acc[0][0] = fmaf(av.x, bv.x, acc[0][0]);
      acc[0][1] = fmaf(av.x, bv.y, acc[0][1]);
      acc[1][0] = fmaf(av.y, bv.x, acc[1][0]);
      acc[1][1] = fmaf(av.y, bv.y, acc[1][1]);
    }
  }
  float2 bq = *(const float2*)&bias[n0+tx*2];
  float sl[2], ql[2];
  #pragma unroll
  for (int i=0;i<2;i++){
    size_t o = (size_t)(m0+ty*2+i)*N + n0 + tx*2;
    float2 ov; ov.x = acc[i][0]+bq.x; ov.y = acc[i][1]+bq.y;
    *(float2*)&out[o] = ov;
    sl[i] = ov.x+ov.y; ql[i] = ov.x*ov.x+ov.y*ov.y;
  }
  #pragma unroll
  for (int o=8;o;o>>=1){
    sl[0]+=__shfl_xor(sl[0],o); ql[0]+=__shfl_xor(ql[0],o);
    sl[1]+=__shfl_xor(sl[1],o); ql[1]+=__shfl_xor(ql[1],o);
  }
  if (tx==0){
    atomicAdd(&su[m0+ty*2],   sl[0]); atomicAdd(&sq[m0+ty*2],   ql[0]);
    atomicAdd(&su[m0+ty*2+1], sl[1]); atomicAdd(&sq[m0+ty*2+1], ql[1]);
  }
}

// ---------------- gemm32 + residual + LN-stat atomics (outproj); grid (M/32,N/32)
__global__ __launch_bounds__(256) void k_gemm32s(const float* __restrict__ act,
                      const float* __restrict__ wt, const float* __restrict__ res,
                      float* __restrict__ out, float* __restrict__ su, float* __restrict__ sq,
                      int K, int N){
  __shared__ float As[32][34];
  __shared__ float Bs[32][32];
  int tid = threadIdx.x;
  int m0 = blockIdx.x*32, n0 = blockIdx.y*32;
  int tx = tid&15, ty = tid>>4;
  int arow = tid>>3, akq = tid&7;
  int brow = tid>>3, bn4 = tid&7;
  float4 aR = *(const float4*)&act[(size_t)(m0+arow)*K + akq*4];
  float4 bR = *(const float4*)&wt [(size_t)brow*N + n0 + bn4*4];
  float acc[2][2] = {{0}};
  for (int k0=0; k0<K; k0+=32){
    __syncthreads();
    As[akq*4+0][arow]=aR.x; As[akq*4+1][arow]=aR.y;
    As[akq*4+2][arow]=aR.z; As[akq*4+3][arow]=aR.w;
    *(float4*)&Bs[brow][bn4*4] = bR;
    __syncthreads();
    if (k0+32 < K){
      aR = *(const float4*)&act[(size_t)(m0+arow)*K + k0+32 + akq*4];
      bR = *(const float4*)&wt [(size_t)(k0+32+brow)*N + n0 + bn4*4];
    }
    #pragma unroll
    for (int kk=0; kk<32; kk++){
      float2 av = *(const float2*)&As[kk][ty*2];
      float2 bv = *(const float2*)&Bs[kk][tx*2];
      acc[0][0] = fmaf(av.x, bv.x, acc[0][0]);
      acc[0][1] = fmaf(av.x, bv.y, acc[0][1]);
      acc[1][0] = fmaf(av.y, bv.x, acc[1][0]);
      acc[1][1] = fmaf(av.y, bv.y, acc[1][1]);
    }
  }
  float sl[2], ql[2];
  #pragma unroll
  for (int i=0;i<2;i++){
    size_t o = (size_t)(m0+ty*2+i)*N + n0 + tx*2;
    float2 r = *(const float2*)&res[o];
    float2 ov; ov.x = acc[i][0]+r.x; ov.y = acc[i][1]+r.y;
    *(float2*)&out[o] = ov;
    sl[i] = ov.x+ov.y; ql[i] = ov.x*ov.x+ov.y*ov.y;
  }
  #pragma unroll
  for (int o=8;o;o>>=1){
    sl[0]+=__shfl_xor(sl[0],o); ql[0]+=__shfl_xor(ql[0],o);
    sl[1]+=__shfl_xor(sl[1],o); ql[1]+=__shfl_xor(ql[1],o);
  }
  if (tx==0){
    atomicAdd(&su[m0+ty*2],   sl[0]); atomicAdd(&sq[m0+ty*2],   ql[0]);
    atomicAdd(&su[m0+ty*2+1], sl[1]); atomicAdd(&sq[m0+ty*2+1], ql[1]);
  }
}

// ---------------- pu GEMM: bias, store un-patchified [c][h][w]; grid (32,48); K=192,N=1536
__global__ __launch_bounds__(256) void k_gemmPU(const float* __restrict__ act,
                      const float* __restrict__ wt, const float* __restrict__ bias,
                      float* __restrict__ out){
  const int K = 192, N = 1536;
  __shared__ float As[32][34];
  __shared__ float Bs[32][32];
  int tid = threadIdx.x;
  int m0 = blockIdx.x*32, n0 = blockIdx.y*32;
  int tx = tid&15, ty = tid>>4;
  int arow = tid>>3, akq = tid&7;
  int brow = tid>>3, bn4 = tid&7;
  float4 aR = *(const float4*)&act[(size_t)(m0+arow)*K + akq*4];
  float4 bR = *(const float4*)&wt [(size_t)brow*N + n0 + bn4*4];
  float acc[2][2] = {{0}};
  for (int k0=0; k0<K; k0+=32){
    __syncthreads();
    As[akq*4+0][arow]=aR.x; As[akq*4+1][arow]=aR.y;
    As[akq*4+2][arow]=aR.z; As[akq*4+3][arow]=aR.w;
    *(float4*)&Bs[brow][bn4*4] = bR;
    __syncthreads();
    if (k0+32 < K){
      aR = *(const float4*)&act[(size_t)(m0+arow)*K + k0+32 + akq*4];
      bR = *(const float4*)&wt [(size_t)(k0+32+brow)*N + n0 + bn4*4];
    }
    #pragma unroll
    for (int kk=0; kk<32; kk++){
      float2 av = *(const float2*)&As[kk][ty*2];
      float2 bv = *(const float2*)&Bs[kk][tx*2];
      acc[0][0] = fmaf(av.x, bv.x, acc[0][0]);
      acc[0][1] = fmaf(av.x, bv.y, acc[0][1]);
      acc[1][0] = fmaf(av.y, bv.x, acc[1][0]);
      acc[1][1] = fmaf(av.y, bv.y, acc[1][1]);
    }
  }
  int n = n0 + tx*2;
  float2 bq = *(const float2*)&bias[n];
  int c = n>>4, i2 = (n>>2)&3, j = n&3;
  #pragma unroll
  for (int i=0;i<2;i++){
    int m = m0+ty*2+i;
    size_t o = ((size_t)c<<14) + (size_t)((m>>5)*4+i2)*128 + (m&31)*4 + j;
    float2 ov; ov.x = acc[i][0]+bq.x; ov.y = acc[i][1]+bq.y;
    *(float2*)&out[o] = ov;
  }
}

// ---------------- gemm32 with layernorm fused on A (stats from raw sums); K%32==0
__global__ __launch_bounds__(256) void k_gemm32ln(const float* __restrict__ act,
                      const float* __restrict__ wt, const float* __restrict__ lg,
                      const float* __restrict__ lb, const float* __restrict__ su,
                      const float* __restrict__ sq, float* __restrict__ out,
                      int K, int N){
  __shared__ float As[32][34];
  __shared__ float Bs[32][32];
  int tid = threadIdx.x;
  int m0 = blockIdx.x*32, n0 = blockIdx.y*32;
  int tx = tid&15, ty = tid>>4;
  int arow = tid>>3, akq = tid&7;
  int brow = tid>>3, bn4 = tid&7;
  float m = su[m0+arow]*(1.f/192.f);
  float r = rsqrtf(sq[m0+arow]*(1.f/192.f) - m*m + 1e-5f);
  float4 aR = *(const float4*)&act[(size_t)(m0+arow)*K + akq*4];
  float4 gR = *(const float4*)&lg[akq*4];
  float4 hR = *(const float4*)&lb[akq*4];
  float4 bR = *(const float4*)&wt[(size_t)brow*N + n0 + bn4*4];
  float acc[2][2] = {{0}};
  for (int k0=0; k0<K; k0+=32){
    __syncthreads();
    As[akq*4+0][arow] = (aR.x-m)*r*gR.x + hR.x;
    As[akq*4+1][arow] = (aR.y-m)*r*gR.y + hR.y;
    As[akq*4+2][arow] = (aR.z-m)*r*gR.z + hR.z;
    As[akq*4+3][arow] = (aR.w-m)*r*gR.w + hR.w;
    *(float4*)&Bs[brow][bn4*4] = bR;
    __syncthreads();
    if (k0+32 < K){
      aR = *(const float4*)&act[(size_t)(m0+arow)*K + k0+32 + akq*4];
      gR = *(const float4*)&lg[k0+32+akq*4];
      hR = *(const float4*)&lb[k0+32+akq*4];
      bR = *(const float4*)&wt[(size_t)(k0+32+brow)*N + n0 + bn4*4];
    }
    #pragma unroll
    for (int kk=0; kk<32; kk++){
      float2 av = *(const float2*)&As[kk][ty*2];
      float2 bv = *(const float2*)&Bs[kk][tx*2];
      acc[0][0] = fmaf(av.x, bv.x, acc[0][0]);
      acc[0][1] = fmaf(av.x, bv.y, acc[0][1]);
      acc[1][0] = fmaf(av.y, bv.x, acc[1][0]);
      acc[1][1] = fmaf(av.y, bv.y, acc[1][1]);
    }
  }
  #pragma unroll
  for (int i=0;i<2;i++){
    size_t o = (size_t)(m0+ty*2+i)*N + n0 + tx*2;
    float2 ov; ov.x = acc[i][0]; ov.y = acc[i][1];
    *(float2*)&out[o] = ov;
  }
}

// ---------------- fused depthwise conv + silu + 2-layout xst build; grid (32 h0, 12 d0), tb (32,8)
__global__ __launch_bounds__(256) void k_dwxst(const float* __restrict__ xz,
                        const float* __restrict__ w, const float* __restrict__ bias,
                        float* __restrict__ xcs, float* __restrict__ xst0,
                        float* __restrict__ xst1){
  __shared__ float ld[96][33];
  __shared__ float t[32][33];
  int h0 = blockIdx.x;
  int d0 = blockIdx.y*32;
  int tx = threadIdx.x, ty = threadIdx.y;
  #pragma unroll
  for (int i=0;i<12;i++){
    int ll = i*8 + ty;
    int h = h0 - 1 + (ll>>5);
    int wv = ll & 31;
    float v = 0.f;
    if ((unsigned)h < 32u) v = xz[(size_t)(h*32+wv)*768 + d0 + tx];
    ld[ll][tx] = v;
  }
  __syncthreads();
  #pragma unroll
  for (int i=0;i<4;i++){
    int dl = ty + 8*i;
    int d = d0 + dl;
    float acc = bias[d];
    const float* wp = w + d*9;
    #pragma unroll
    for (int di=0;di<3;di++){
      #pragma unroll
      for (int dj=0;dj<3;dj++){
        int wq = tx + dj - 1;
        if ((unsigned)wq < 32u)
          acc = fmaf(ld[di*32 + wq][dl], wp[di*3+dj], acc);
      }
    }
    float val = silu_(acc);
    xcs[(size_t)d*L_ + h0*32 + tx] = val;
    t[dl][tx] = val;
  }
  __syncthreads();
  int d = d0 + tx;
  #pragma unroll
  for (int i=0;i<4;i++){
    int wq = ty + 8*i;
    int l = h0*32 + wq;
    float val = t[tx][wq];
    int t1 = wq*32 + h0;
    xst0[(size_t)l*DI_ + d] = val;
    xst1[(size_t)t1*DI_ + d] = val;
  }
}

// ---------------- x_dbl partial (split-K over d, 3 x 128): grid (4, 11, 12)
__global__ __launch_bounds__(256) void k_xdblP(const float* __restrict__ xcs,
                       const float* __restrict__ xw, float* __restrict__ xdblP){
  int kz = blockIdx.z;
  int k = kz & 3, sp = kz >> 2;
  int s = blockIdx.x*256 + threadIdx.x;
  int Ts = ((s&31)<<5) | (s>>5);
  int lw;
  if (k==0) lw = s;
  else if (k==1) lw = Ts;
  else if (k==2) lw = 1023-s;
  else lw = 1023-Ts;
  int c0 = blockIdx.y*4;
  const float* wp = xw + ((size_t)k*CXP_ + c0)*DI_ + sp*128;
  const float* src = xcs + s + (size_t)sp*128*L_;
  float a0=0,a1=0,a2=0,a3=0;
  for (int d=0; d<128; d++){
    float v = src[(size_t)d*L_];
    a0 = fmaf(v, wp[d],        a0);
    a1 = fmaf(v, wp[DI_+d],    a1);
    a2 = fmaf(v, wp[2*DI_+d],  a2);
    a3 = fmaf(v, wp[3*DI_+d],  a3);
  }
  size_t base = (((size_t)sp*4 + k)*CXP_ + c0)*L_ + lw;
  xdblP[base]       = a0;
  xdblP[base+L_]    = a1;
  xdblP[base+2*L_]  = a2;
  xdblP[base+3*L_]  = a3;
}

// ---------------- combine partials + dt proj + softplus -> dts_t; repack B,C -> bc
__global__ void k_dtbc(const float* __restrict__ xdblP, const float* __restrict__ dtw,
                       const float* __restrict__ dtb, float* __restrict__ dts_t,
                       float* __restrict__ bc){
  int k = blockIdx.y, l = blockIdx.x, d = threadIdx.x;
  const float* p0 = xdblP + ((size_t)(0+k)*CXP_)*L_ + l;
  const float* p1 = xdblP + ((size_t)(4+k)*CXP_)*L_ + l;
  const float* p2 = xdblP + ((size_t)(8+k)*CXP_)*L_ + l;
  float acc = dtb[(size_t)k*DI_ + d];
  const float* w = dtw + ((size_t)k*DI_ + d)*R_;
  #pragma unroll
  for (int r=0;r<R_;r++){
    size_t o = (size_t)r*L_;
    acc = fmaf(p0[o]+p1[o]+p2[o], w[r], acc);
  }
  dts_t[((size_t)k*L_ + l)*DI_ + d] = softplus_(acc);
  if (d < 32){
    size_t o = (size_t)(R_+d)*L_;
    bc[((size_t)k*L_ + l)*32 + d] = p0[o]+p1[o]+p2[o];
  }
}

// ---------------- chunked selective scan, phase A
__global__ __launch_bounds__(256) void k_scanA(const float* __restrict__ xst0,
                      const float* __restrict__ xst1,
                      const float* __restrict__ dts_t, const float* __restrict__ bc,
                      const float* __restrict__ Alog,
                      float* __restrict__ Ech, float* __restrict__ Hch){
  int k = blockIdx.z;
  int d = blockIdx.y*16 + (threadIdx.x>>4);
  int n = threadIdx.x&15;
  int ch = blockIdx.x;
  float A = -expf(Alog[((size_t)k*DI_ + d)*NS_ + n]);
  float aL2 = A * 1.4426950408889634f;
  int t0 = ch*TC_;
  const float* dtp = dts_t + ((size_t)k*L_ + t0)*DI_ + d;
  const float* bcp = bc    + ((size_t)k*L_ + t0)*32;
  const float* xb = (k&1) ? xst1 : xst0;
  const float* xp_; ptrdiff_t xs_;
  if (k < 2){ xp_ = xb + (size_t)t0*DI_ + d; xs_ = DI_; }
  else      { xp_ = xb + (size_t)(1023-t0)*DI_ + d; xs_ = -(ptrdiff_t)DI_; }
  float h = 0.f, Ep = 1.f;
  #pragma unroll 4
  for (int t=0;t<TC_;t++){
    float dt = dtp[(size_t)t*DI_];
    float xv = xp_[(ptrdiff_t)t*xs_];
    float Bn = bcp[t*32+n];
    float e = exp2f(aL2*dt);
    h = fmaf(e, h, dt*xv*Bn);
    Ep *= e;
  }
  size_t idx = (((size_t)k*NCH_ + ch)*DI_ + d)*NS_ + n;
  Ech[idx] = Ep; Hch[idx] = h;
}

// ---------------- phase B: fold chunk aggregates -> carry-in per chunk
__global__ void k_scanB(const float* __restrict__ Ech, const float* __restrict__ Hch,
                        float* __restrict__ carry){
  int idx = blockIdx.x*256 + threadIdx.x;
  int k = idx / (DI_*NS_);
  int dn = idx % (DI_*NS_);
  float h = 0.f;
  #pragma unroll
  for (int c=0;c<NCH_;c++){
    size_t o = ((size_t)(k*NCH_+c)*DI_*NS_) + dn;
    carry[o] = h;
    h = fmaf(Ech[o], h, Hch[o]);
  }
}

// ---------------- phase C: recompute with carry-in, emit y
__global__ __launch_bounds__(256) void k_scanC(const float* __restrict__ xst0,
                      const float* __restrict__ xst1,
                      const float* __restrict__ dts_t, const float* __restrict__ bc,
                      const float* __restrict__ Alog, const float* __restrict__ carry,
                      float* __restrict__ yst){
  int k = blockIdx.z;
  int d = blockIdx.y*16 + (threadIdx.x>>4);
  int n = threadIdx.x&15;
  int ch = blockIdx.x;
  float A = -expf(Alog[((size_t)k*DI_ + d)*NS_ + n]);
  float aL2 = A * 1.4426950408889634f;
  int t0 = ch*TC_;
  const float* dtp = dts_t + ((size_t)k*L_ + t0)*DI_ + d;
  const float* bcp = bc    + ((size_t)k*L_ + t0)*32;
  const float* xb = (k&1) ? xst1 : xst0;
  const float* xp_; ptrdiff_t xs_;
  if (k < 2){ xp_ = xb + (size_t)t0*DI_ + d; xs_ = DI_; }
  else      { xp_ = xb + (size_t)(1023-t0)*DI_ + d; xs_ = -(ptrdiff_t)DI_; }
  float* yp = yst + ((size_t)k*L_ + t0)*DI_ + d;
  float h = carry[(((size_t)k*NCH_ + ch)*DI_ + d)*NS_ + n];
  #pragma unroll 4
  for (int t=0;t<TC_;t++){
    float dt = dtp[(size_t)t*DI_];
    float xv = xp_[(ptrdiff_t)t*xs_];
    float Bn = bcp[t*32+n], Cn = bcp[t*32+16+n];
    float e = exp2f(aL2*dt);
    h = fmaf(e, h, dt*xv*Bn);
    float p = h*Cn;
    p += __shfl_xor(p,1); p += __shfl_xor(p,2);
    p += __shfl_xor(p,4); p += __shfl_xor(p,8);
    if (n==0) yp[(size_t)t*DI_] = p;
  }
}

// ---------------- merge 4 dirs + Dskip + LN + silu(z) gate; zeroes LN-sum bufs
__global__ void k_merge(const float* __restrict__ yst, const float* __restrict__ xst0,
                        const float* __restrict__ xst1,
                        const float* __restrict__ Dsk, const float* __restrict__ mw,
                        const float* __restrict__ ong, const float* __restrict__ onb,
                        const float* __restrict__ xz, float* __restrict__ out,
                        float* __restrict__ su, float* __restrict__ sq){
  int l = blockIdx.x, d = threadIdx.x;
  if (d == 0){ su[l] = 0.f; sq[l] = 0.f; }
  int T = ((l&31)<<5) | (l>>5);
  int tt[4] = { l, T, 1023-l, 1023-T };
  float xv0 = xst0[(size_t)l*DI_ + d];
  float xv1 = xst1[(size_t)T*DI_ + d];
  float v = 0.f;
  #pragma unroll
  for (int k=0;k<4;k++){
    float xk = (k&1) ? xv1 : xv0;
    v += mw[k]*(yst[(size_t)(k*L_ + tt[k])*DI_ + d] + xk*Dsk[k*DI_+d]);
  }
  float s = v, sqv = v*v;
  for (int o=32;o;o>>=1){ s += __shfl_xor(s,o); sqv += __shfl_xor(sqv,o); }
  __shared__ float rs_[6], rq_[6];
  int lane = d&63, wid = d>>6;
  if (!lane){ rs_[wid]=s; rq_[wid]=sqv; }
  __syncthreads();
  float ts=0.f, tq=0.f;
  #pragma unroll
  for (int i=0;i<6;i++){ ts += rs_[i]; tq += rq_[i]; }
  float mu = ts*(1.f/DI_);
  float rstd = rsqrtf(tq*(1.f/DI_) - mu*mu + 1e-5f);
  float y = (v-mu)*rstd*ong[d] + onb[d];
  float z = xz[(size_t)l*768 + DI_ + d];
  out[(size_t)l*DI_ + d] = y * silu_(z);
}

// ---------------- residual + attention + bn2 (xu already in [c][h][w])
__global__ void k_sum(const float* __restrict__ x, const float* __restrict__ h,
                      const float* __restrict__ attn, const float* __restrict__ xu,
                      const float* g2, const float* b2, const float* m2, const float* v2,
                      float* __restrict__ xsum, float* __restrict__ h2){
  int idx = blockIdx.x*256 + threadIdx.x;
  int c = idx>>14;
  float s = x[idx] + h[idx]*attn[c] + xu[idx];
  xsum[idx] = s;
  h2[idx] = (s - m2[c])*rsqrtf(v2[c]+1e-5f)*g2[c] + b2[c];
}

// ---------------- scpa: dual 1x1 conv + lrelu; 6+6 oc per block; grid (64,8) sp-major
__global__ __launch_bounds__(256) void k_1x1ab(const float* __restrict__ h2,
                        const float* __restrict__ wa, const float* __restrict__ wb,
                        float* __restrict__ a, float* __restrict__ b){
  __shared__ float lw[96*12];
  int ocg = blockIdx.y;
  for (int i=threadIdx.x; i<96*12; i+=256){
    int o = i%12, c = i/12;
    lw[i] = (o<6) ? wa[(ocg*6 + o)*96 + c] : wb[(ocg*6 + (o-6))*96 + c];
  }
  __syncthreads();
  int p = blockIdx.x*256 + threadIdx.x;
  float acc[12];
  #pragma unroll
  for (int o=0;o<12;o++) acc[o]=0.f;
  for (int c=0;c<96;c++){
    float v = h2[(size_t)c*HW + p];
    const float* w = lw + c*12;
    #pragma unroll
    for (int o=0;o<12;o++) acc[o] = fmaf(v, w[o], acc[o]);
  }
  #pragma unroll
  for (int o=0;o<6;o++){
    a[(size_t)(ocg*6+o)*HW + p] = lrelu_(acc[o]);
    b[(size_t)(ocg*6+o)*HW + p] = lrelu_(acc[6+o]);
  }
}

// ---------------- scpa: 1x1 conv + bias + sigmoid (gate); grid (64,8) sp-major
__global__ __launch_bounds__(256) void k_1x1g(const float* __restrict__ b,
                       const float* __restrict__ w, const float* __restrict__ bias,
                       float* __restrict__ g){
  __shared__ float lw[48*6];
  int ocg = blockIdx.y;
  for (int i=threadIdx.x; i<48*6; i+=256){
    int o = i%6, c = i/6;
    lw[i] = w[(ocg*6 + o)*48 + c];
  }
  __syncthreads();
  int p = blockIdx.x*256 + threadIdx.x;
  float acc[6];
  #pragma unroll
  for (int o=0;o<6;o++) acc[o] = bias[ocg*6+o];
  for (int c=0;c<48;c++){
    float v = b[(size_t)c*HW + p];
    const float* wp = lw + c*6;
    #pragma unroll
    for (int o=0;o<6;o++) acc[o] = fmaf(v, wp[o], acc[o]);
  }
  #pragma unroll
  for (int o=0;o<6;o++) g[(size_t)(ocg*6+o)*HW + p] = sigmoid_(acc[o]);
}

// ---------------- scpa: DUAL 3x3 conv (k1 + k3 paths), 8-ic batched LDS staging
// grid (64 sp, 16 half*ocg) — spatial-major so tile-sharing blocks land on one XCD
__global__ __launch_bounds__(256) void k_conv3d(const float* __restrict__ inA,
                        const float* __restrict__ wA, const float* __restrict__ inB,
                        const float* __restrict__ wB, const float* __restrict__ aux,
                        float* __restrict__ outA, float* __restrict__ outB){
  __shared__ float lw[48*9*6];
  __shared__ float ld[8][4][130];
  int sp = blockIdx.x;
  int half = blockIdx.y >> 3;
  int ocg = blockIdx.y & 7;
  const float* in = half ? inB : inA;
  const float* w  = half ? wB : wA;
  int tid = threadIdx.x;
  for (int i=tid; i<48*9*6; i+=256){
    int o = i%6, j = (i/6)%9, ic = i/54;
    lw[i] = w[((size_t)(ocg*6+o)*48 + ic)*9 + j];
  }
  if (tid < 32){ ld[tid>>2][tid&3][0] = 0.f; ld[tid>>2][tid&3][129] = 0.f; }
  int p = sp*256 + tid;
  int ww = p&127;
  int hbase = sp*2 - 1;                      // rows hbase..hbase+3
  int lr = 1 + (tid>>7);                     // this thread's center row in ld
  float acc[6];
  #pragma unroll
  for (int o=0;o<6;o++) acc[o]=0.f;
  for (int ic0=0; ic0<48; ic0+=8){
    __syncthreads();
    #pragma unroll
    for (int q=0;q<16;q++){
      int i = tid + q*256;
      int icl = i>>9, rem = i&511;
      int r = rem>>7, cp = rem&127;
      int gy = hbase + r;
      ld[icl][r][cp+1] = ((unsigned)gy < 128u) ? in[(size_t)(ic0+icl)*HW + gy*128 + cp] : 0.f;
    }
    __syncthreads();
    #pragma unroll
    for (int icl=0; icl<8; icl++){
      const float* lwp = lw + (ic0+icl)*54;
      #pragma unroll
      for (int di=0;di<3;di++){
        #pragma unroll
        for (int dj=0;dj<3;dj++){
          float xv = ld[icl][lr-1+di][ww+dj];
          const float* wj = lwp + (di*3+dj)*6;
          #pragma unroll
          for (int o=0;o<6;o++) acc[o] = fmaf(xv, wj[o], acc[o]);
        }
      }
    }
  }
  if (half == 0){
    #pragma unroll
    for (int o=0;o<6;o++)
      outA[(size_t)(ocg*6+o)*HW + p] = lrelu_(acc[o]);
  } else {
    #pragma unroll
    for (int o=0;o<6;o++){
      size_t oi = (size_t)(ocg*6+o)*HW + p;
      outB[oi] = acc[o]*aux[oi];
    }
  }
}

// ---------------- scpa: single 3x3 conv (k4, lrelu); grid (64 sp, 8 ocg)
__global__ __launch_bounds__(256) void k_conv3(const float* __restrict__ in,
                        const float* __restrict__ w, float* __restrict__ out){
  __shared__ float lw[48*9*6];
  __shared__ float ld[8][4][130];
  int sp = blockIdx.x;
  int ocg = blockIdx.y;
  int tid = threadIdx.x;
  for (int i=tid; i<48*9*6; i+=256){
    int o = i%6, j = (i/6)%9, ic = i/54;
    lw[i] = w[((size_t)(ocg*6+o)*48 + ic)*9 + j];
  }
  if (tid < 32){ ld[tid>>2][tid&3][0] = 0.f; ld[tid>>2][tid&3][129] = 0.f; }
  int p = sp*256 + tid;
  int ww = p&127;
  int hbase = sp*2 - 1;
  int lr = 1 + (tid>>7);
  float acc[6];
  #pragma unroll
  for (int o=0;o<6;o++) acc[o]=0.f;
  for (int ic0=0; ic0<48; ic0+=8){
    __syncthreads();
    #pragma unroll
    for (int q=0;q<16;q++){
      int i = tid + q*256;
      int icl = i>>9, rem = i&511;
      int r = rem>>7, cp = rem&127;
      int gy = hbase + r;
      ld[icl][r][cp+1] = ((unsigned)gy < 128u) ? in[(size_t)(ic0+icl)*HW + gy*128 + cp] : 0.f;
    }
    __syncthreads();
    #pragma unroll
    for (int icl=0; icl<8; icl++){
      const float* lwp = lw + (ic0+icl)*54;
      #pragma unroll
      for (int di=0;di<3;di++){
        #pragma unroll
        for (int dj=0;dj<3;dj++){
          float xv = ld[icl][lr-1+di][ww+dj];
          const float* wj = lwp + (di*3+dj)*6;
          #pragma unroll
          for (int o=0;o<6;o++) acc[o] = fmaf(xv, wj[o], acc[o]);
        }
      }
    }
  }
  #pragma unroll
  for (int o=0;o<6;o++)
    out[(size_t)(ocg*6+o)*HW + p] = lrelu_(acc[o]);
}

// ---------------- final 1x1 conv + both residuals; grid (64,8) sp-major
__global__ __launch_bounds__(256) void k_c3(const float* __restrict__ ab,
                     const float* __restrict__ w, const float* __restrict__ h2,
                     const float* __restrict__ xsum, float* __restrict__ out){
  __shared__ float lw[96*12];
  int ocg = blockIdx.y;
  for (int i=threadIdx.x; i<96*12; i+=256){
    int o = i%12, j = i/12;
    lw[i] = w[(ocg*12 + o)*96 + j];
  }
  __syncthreads();
  int p = blockIdx.x*256 + threadIdx.x;
  float acc[12];
  #pragma unroll
  for (int o=0;o<12;o++) acc[o]=0.f;
  for (int j=0;j<96;j++){
    float v = ab[(size_t)j*HW + p];
    const float* wp = lw + j*12;
    #pragma unroll
    for (int o=0;o<12;o++) acc[o] = fmaf(v, wp[o], acc[o]);
  }
  #pragma unroll
  for (int o=0;o<12;o++){
    size_t oi = (size_t)(ocg*12+o)*HW + p;
    out[oi] = acc[o] + h2[oi] + xsum[oi];
  }
}

extern "C" void kernel_launch(void* const* d_in, const int* in_sizes, int n_in,
                              void* d_out, int out_size, void* d_ws, size_t ws_size,
                              hipStream_t stream){
  (void)in_sizes; (void)n_in; (void)out_size; (void)ws_size;
  const float* x    = (const float*)d_in[0];
  const float* bn1g = (const float*)d_in[1];
  const float* bn1b = (const float*)d_in[2];
  const float* bn1m = (const float*)d_in[3];
  const float* bn1v = (const float*)d_in[4];
  const float* caw1 = (const float*)d_in[5];
  const float* caw2 = (const float*)d_in[6];
  const float* peW  = (const float*)d_in[7];
  const float* peb  = (const float*)d_in[8];
  const float* puW  = (const float*)d_in[9];
  const float* pub  = (const float*)d_in[10];
  const float* lng  = (const float*)d_in[11];
  const float* lnb  = (const float*)d_in[12];
  const float* inW  = (const float*)d_in[13];
  const float* convw= (const float*)d_in[14];
  const float* convb= (const float*)d_in[15];
  const float* xprojw=(const float*)d_in[16];
  const float* dtw  = (const float*)d_in[17];
  const float* dtb  = (const float*)d_in[18];
  const float* Alog = (const float*)d_in[19];
  const float* Dsk  = (const float*)d_in[20];
  const float* ong  = (const float*)d_in[21];
  const float* onb  = (const float*)d_in[22];
  const float* outW = (const float*)d_in[23];
  const float* mw   = (const float*)d_in[24];
  const float* bn2g = (const float*)d_in[25];
  const float* bn2b = (const float*)d_in[26];
  const float* bn2m = (const float*)d_in[27];
  const float* bn2v = (const float*)d_in[28];
  const float* c1a  = (const float*)d_in[29];
  const float* c1b  = (const float*)d_in[30];
  const float* k1w  = (const float*)d_in[31];
  const float* k2w  = (const float*)d_in[32];
  const float* k2b  = (const float*)d_in[33];
  const float* k3w  = (const float*)d_in[34];
  const float* k4w  = (const float*)d_in[35];
  const float* c3w  = (const float*)d_in[36];
  float* out = (float*)d_out;

  float* ws = (float*)d_ws;
  size_t off = 0;
  auto alloc = [&](size_t n){ float* p = ws + off; off += n; return p; };
  float* peWT  = alloc((size_t)1536*192);
  float* puWT  = alloc((size_t)192*1536);
  float* inWT  = alloc((size_t)8*192*768);
  float* outWT = alloc((size_t)8*384*192);
  float* bufH  = alloc((size_t)96*HW);
  float* stats = alloc(256);
  float* attn  = alloc(128);
  float* bufP  = alloc((size_t)1024*1536);   // xu ([c][h][w] layout)
  float* x2a   = alloc((size_t)1024*192);
  float* x2b   = alloc((size_t)1024*192);
  float* bufXZ = alloc((size_t)1024*768);
  float* bufXCS= alloc((size_t)384*1024);
  float* bufXST= alloc((size_t)4*1024*384);  // xst0|xst1 (half used); later ab (96ch)
  float* xdblP = alloc((size_t)12*44*1024);
  float* dts   = alloc((size_t)4*1024*384);  // scan dts; scpa a|b
  float* bc    = alloc((size_t)4*1024*32);
  float* yst   = alloc((size_t)4*1024*384);  // scan y; scpa g|t
  float* bufY  = alloc((size_t)1024*384);
  float* xsum  = alloc((size_t)96*HW);
  float* h2    = alloc((size_t)96*HW);
  float* Ech   = alloc((size_t)K_*NCH_*DI_*NS_);
  float* Hch   = alloc((size_t)K_*NCH_*DI_*NS_);
  float* carry = alloc((size_t)K_*NCH_*DI_*NS_);
  float* suB   = alloc(1024);
  float* sqB   = alloc(1024);
  float* xst0  = bufXST;
  float* xst1  = bufXST + (size_t)L_*DI_;

  dim3 tb(32,8);
  k_transAll<<<2304, tb, 0, stream>>>(peW, peWT, puW, puWT, inW, inWT, outW, outWT);

  k_bn1<<<96,256,0,stream>>>(x, bn1g, bn1b, bn1m, bn1v, bufH, stats, suB, sqB);
  k_attn<<<1,128,0,stream>>>(stats, caw1, caw2, attn);
  k_gemmPE<<<dim3(32,6),256,0,stream>>>(bufH, peWT, peb, x2a, suB, sqB);

  float* cur = x2a; float* nxt = x2b;
  for (int b=0;b<8;b++){
    k_gemm32ln<<<dim3(32,24),256,0,stream>>>(cur, inWT+(size_t)b*192*768,
                        lng+(size_t)b*192, lnb+(size_t)b*192, suB, sqB, bufXZ, 192, 768);
    k_dwxst<<<dim3(32,12),tb,0,stream>>>(bufXZ, convw+(size_t)b*384*9,
                        convb+(size_t)b*384, bufXCS, xst0, xst1);
    k_xdblP<<<dim3(4,11,12),256,0,stream>>>(bufXCS, xprojw+(size_t)b*4*44*384, xdblP);
    k_dtbc<<<dim3(1024,4),384,0,stream>>>(xdblP, dtw+(size_t)b*4*384*12, dtb+(size_t)b*4*384, dts, bc);
    const float* Ab = Alog + (size_t)b*4*384*16;
    k_scanA<<<dim3(NCH_,DI_/16,4),256,0,stream>>>(xst0, xst1, dts, bc, Ab, Ech, Hch);
    k_scanB<<<(K_*DI_*NS_)/256,256,0,stream>>>(Ech, Hch, carry);
    k_scanC<<<dim3(NCH_,DI_/16,4),256,0,stream>>>(xst0, xst1, dts, bc, Ab, carry, yst);
    k_merge<<<1024,384,0,stream>>>(yst, xst0, xst1, Dsk+(size_t)b*4*384, mw+(size_t)b*4,
                                   ong+(size_t)b*384, onb+(size_t)b*384, bufXZ, bufY, suB, sqB);
    k_gemm32s<<<dim3(32,6),256,0,stream>>>(bufY, outWT+(size_t)b*384*192, cur, nxt, suB, sqB, 384, 192);
    float* t = cur; cur = nxt; nxt = t;
  }

  k_gemmPU<<<dim3(32,48),256,0,stream>>>(cur, puWT, pub, bufP);
  k_sum<<<(96*HW)/256,256,0,stream>>>(x, bufH, attn, bufP, bn2g, bn2b, bn2m, bn2v, xsum, h2);

  float* bufA = dts;
  float* bufB = dts + (size_t)48*HW;
  float* bufG = yst;
  float* bufT = yst + (size_t)48*HW;
  float* ab   = bufXST;
  k_1x1ab<<<dim3(64,8),256,0,stream>>>(h2, c1a, c1b, bufA, bufB);
  k_1x1g<<<dim3(64,8),256,0,stream>>>(bufB, k2w, k2b, bufG);
  k_conv3d<<<dim3(64,16),256,0,stream>>>(bufA, k1w, bufB, k3w, bufG, ab, bufT);
  k_conv3<<<dim3(64,8),256,0,stream>>>(bufT, k4w, ab+(size_t)48*HW);
  k_c3<<<dim3(64,8),256,0,stream>>>(ab, c3w, h2, xsum, out);
}